// Round 17
// baseline (289.017 us; speedup 1.0000x reference)
//
#include <hip/hip_runtime.h>
#include <hip/hip_cooperative_groups.h>
#include <math.h>

#define DIM 1024
#define SEQ 2048
#define BATCH 4
#define ROWS (BATCH*SEQ)        // 8192
#define CHUNKS 128
#define CLEN (SEQ/CHUNKS)       // 16
#define N3 3072                 // fused act width: [value | kplin | qplin]
#define LN_EPS 1e-5f
#define NTK 16                  // K/BK = 1024/64 K-tiles

typedef unsigned short ushort_t;
typedef __attribute__((ext_vector_type(8))) short bf16x8;
typedef __attribute__((ext_vector_type(4))) float f32x4;

static const size_t NE = (size_t)ROWS * DIM;   // 8.4M
static const size_t WN = (size_t)DIM * DIM;    // 1M

// fp32 -> bf16 round-to-nearest-even
__device__ inline ushort_t f2bf(float f) {
    union { float f; unsigned u; } v; v.f = f;
    unsigned r = v.u + 0x7FFFu + ((v.u >> 16) & 1u);
    return (ushort_t)(r >> 16);
}
__device__ inline float bf2f(ushort_t u) { return __uint_as_float((unsigned)u << 16); }

// ---------------------------------------------------------------------------
// ALL prep work in one dispatch (block-range indexed, block-uniform):
//   blocks [0, 6144)        : fp32->bf16 conv  x | Wv | Wo | Wkm | Wqm
//   blocks [6144, 8192)     : transposed conv Wk, Wq  (32x32 tiles)
//   blocks [8192, 8704)     : combined-bias matvecs bck, bcq
// ---------------------------------------------------------------------------
__global__ __launch_bounds__(256)
void prep_all_k(const float* __restrict__ x,   const float* __restrict__ Wv,
                const float* __restrict__ Wo,  const float* __restrict__ Wkm,
                const float* __restrict__ Wqm, const float* __restrict__ Wk,
                const float* __restrict__ Wq,  const float* __restrict__ bk,
                const float* __restrict__ bkm, const float* __restrict__ bq,
                const float* __restrict__ bqm,
                ushort_t* __restrict__ xbf,   ushort_t* __restrict__ W3,
                ushort_t* __restrict__ wo_b,  ushort_t* __restrict__ wkm_b,
                ushort_t* __restrict__ wqm_b, ushort_t* __restrict__ wkT,
                ushort_t* __restrict__ wqT,
                float* __restrict__ bck, float* __restrict__ bcq)
{
    const int blk = blockIdx.x;
    const int t = threadIdx.x;
    __shared__ ushort_t tile[32][33];

    if (blk < 6144) {
        size_t e = ((size_t)blk * 256 + t) * 8;
        const float* src; ushort_t* dst; size_t off;
        if      (e < NE)          { src = x;   dst = xbf;   off = e; }
        else if (e < NE + WN)     { src = Wv;  dst = W3;    off = e - NE; }
        else if (e < NE + 2*WN)   { src = Wo;  dst = wo_b;  off = e - NE - WN; }
        else if (e < NE + 3*WN)   { src = Wkm; dst = wkm_b; off = e - NE - 2*WN; }
        else                      { src = Wqm; dst = wqm_b; off = e - NE - 3*WN; }
        float4 a = *(const float4*)(src + off);
        float4 b = *(const float4*)(src + off + 4);
        ushort4 lo, hi;
        lo.x = f2bf(a.x); lo.y = f2bf(a.y); lo.z = f2bf(a.z); lo.w = f2bf(a.w);
        hi.x = f2bf(b.x); hi.y = f2bf(b.y); hi.z = f2bf(b.z); hi.w = f2bf(b.w);
        *(ushort4*)(dst + off) = lo;
        *(ushort4*)(dst + off + 4) = hi;
    } else if (blk < 8192) {
        int tb = blk - 6144;                  // 0..2047
        const float* in = (tb >> 10) ? Wq : Wk;
        ushort_t* out   = (tb >> 10) ? wqT : wkT;
        int tid = tb & 1023;
        int bx = tid & 31, by = tid >> 5;
        int tx = t & 31, ty = t >> 5;         // 32x8
        #pragma unroll
        for (int j = 0; j < 4; ++j) {
            int r = by * 32 + ty + j * 8;
            tile[ty + j * 8][tx] = f2bf(in[(size_t)r * DIM + bx * 32 + tx]);
        }
        __syncthreads();
        #pragma unroll
        for (int j = 0; j < 4; ++j) {
            int r = bx * 32 + ty + j * 8;
            out[(size_t)r * DIM + by * 32 + tx] = tile[tx][ty + j * 8];
        }
    } else {
        int mb = blk - 8192;                  // 0..511
        int z = mb >> 8;
        const float* Wm  = z ? Wqm : Wkm;
        const float* bi  = z ? bq  : bk;
        const float* bo_ = z ? bqm : bkm;
        float* bc        = z ? bcq : bck;
        int e = (mb & 255) * 4 + (t >> 6);
        int l = t & 63;
        float s = 0.f;
        #pragma unroll
        for (int j = 0; j < DIM / 64; ++j)
            s += Wm[(size_t)e * DIM + l + j * 64] * bi[l + j * 64];
        #pragma unroll
        for (int o = 32; o >= 1; o >>= 1) s += __shfl_down(s, o);
        if (l == 0) bc[e] = s + bo_[e];
    }
}

// ---------------------------------------------------------------------------
// Dual weight-combine GEMM (m97 structure), z selects (Wkm@Wk | Wqm@Wq).
// ---------------------------------------------------------------------------
__global__ __launch_bounds__(256)
void gemm_combine2(const ushort_t* __restrict__ A0, const ushort_t* __restrict__ W0,
                   ushort_t* __restrict__ C0,
                   const ushort_t* __restrict__ A1, const ushort_t* __restrict__ W1,
                   ushort_t* __restrict__ C1)
{
    const ushort_t* A = blockIdx.z ? A1 : A0;
    const ushort_t* W = blockIdx.z ? W1 : W0;
    ushort_t*       C = blockIdx.z ? C1 : C0;
    __shared__ ushort_t As[128 * 32];
    __shared__ ushort_t Bs[128 * 32];
    const int bm = blockIdx.x * 128;
    const int bn = blockIdx.y * 128;
    const int t = threadIdx.x;
    const int lane = t & 63;
    const int w = t >> 6, wr = w >> 1, wc = w & 1;
    f32x4 acc[4][4] = {};
    const int fr = lane & 15;
    const int kc = (lane >> 4) * 8;
    for (int k0 = 0; k0 < DIM; k0 += 32) {
        #pragma unroll
        for (int i = 0; i < 2; ++i) {
            int c = t + i * 256;
            int row = c >> 2;
            int col = (c & 3) * 8;
            const ushort_t* ga = A + (size_t)(bm + row) * DIM + k0 + col;
            __builtin_amdgcn_global_load_lds(
                (const __attribute__((address_space(1))) void*)ga,
                (__attribute__((address_space(3))) void*)(As + (size_t)c * 8), 16, 0, 0);
            const ushort_t* gb = W + (size_t)(bn + row) * DIM + k0 + col;
            __builtin_amdgcn_global_load_lds(
                (const __attribute__((address_space(1))) void*)gb,
                (__attribute__((address_space(3))) void*)(Bs + (size_t)c * 8), 16, 0, 0);
        }
        __syncthreads();
        bf16x8 af[4], bw[4];
        #pragma unroll
        for (int m2 = 0; m2 < 4; ++m2)
            af[m2] = *(const bf16x8*)(As + (wr * 64 + m2 * 16 + fr) * 32 + kc);
        #pragma unroll
        for (int n2 = 0; n2 < 4; ++n2)
            bw[n2] = *(const bf16x8*)(Bs + (wc * 64 + n2 * 16 + fr) * 32 + kc);
        #pragma unroll
        for (int m2 = 0; m2 < 4; ++m2)
            #pragma unroll
            for (int n2 = 0; n2 < 4; ++n2)
                acc[m2][n2] = __builtin_amdgcn_mfma_f32_16x16x32_bf16(
                    af[m2], bw[n2], acc[m2][n2], 0, 0, 0);
        __syncthreads();
    }
    const int fc = lane & 15;
    const int r0 = (lane >> 4) * 4;
    #pragma unroll
    for (int m2 = 0; m2 < 4; ++m2)
        #pragma unroll
        for (int n2 = 0; n2 < 4; ++n2) {
            int col = bn + wc * 64 + n2 * 16 + fc;
            #pragma unroll
            for (int r = 0; r < 4; ++r) {
                int row = bm + wr * 64 + m2 * 16 + r0 + r;
                C[(size_t)row * DIM + col] = f2bf(acc[m2][n2][r]);
            }
        }
}

// ---------------------------------------------------------------------------
// 8-phase counted-vmcnt bf16 MFMA GEMM (NT), K=1024, BM=256, BN in {192,128}.
// (R10/R12 structure verbatim - verified 0 conflicts, minimal FETCH, 831 TF.)
// MODE 6: bf16 out, +bias col<1024.  MODE 4: f32 out, +bias, +bf16 resid.
// ---------------------------------------------------------------------------
template<int MODE, int BN>
__global__ __launch_bounds__(512)
void gemm_pipe(const ushort_t* __restrict__ A, const ushort_t* __restrict__ W,
               const float* __restrict__ bias, const ushort_t* __restrict__ resid,
               void* __restrict__ Cout, int N)
{
    constexpr int NF   = BN / 64;                 // n-frags per wave (3 or 2)
    constexpr int BUFU = 16384 + BN * 64;         // ushorts per buffer
    __shared__ __align__(16) ushort_t lds[2 * BUFU];

    const int bm = blockIdx.x * 256;
    const int bn = blockIdx.y * BN;
    const int t = threadIdx.x;          // 0..511
    const int lane = t & 63;
    const int w = t >> 6;               // 0..7
    const int wr = w >> 2;              // 0..1 (M)
    const int wc = w & 3;               // 0..3 (N)
    const int fr = lane & 15;
    const int hi = lane >> 4;           // 0..3

    f32x4 acc[8][NF] = {};

    auto SA = [&](int kt, ushort_t* buf, int h) {
        #pragma unroll
        for (int i = 0; i < 2; ++i) {
            int c = t + i * 512;                  // 0..1023
            int row = c >> 2, sl = c & 3, sg = sl ^ ((row >> 1) & 3);
            const ushort_t* g = A + (size_t)(bm + row) * 1024 + kt * 64 + h * 32 + sg * 8;
            __builtin_amdgcn_global_load_lds(
                (const __attribute__((address_space(1))) void*)g,
                (__attribute__((address_space(3))) void*)(buf + h * 8192 + (size_t)c * 8),
                16, 0, 0);
        }
    };
    auto SBfull = [&](int kt, ushort_t* buf) {
        #pragma unroll
        for (int i = 0; i < 3; ++i) {
            int c = t + i * 512;                  // 0..1535
            int row = c >> 3, sl = c & 7, sg = sl ^ (row & 7);
            const ushort_t* g = W + (size_t)(bn + row) * 1024 + kt * 64 + sg * 8;
            __builtin_amdgcn_global_load_lds(
                (const __attribute__((address_space(1))) void*)g,
                (__attribute__((address_space(3))) void*)(buf + 16384 + (size_t)c * 8),
                16, 0, 0);
        }
    };
    auto SBh = [&](int kt, ushort_t* buf, int h) {
        int c = t;                                // 0..511
        int row = c >> 2, sl = c & 3, sg = sl ^ ((row >> 1) & 3);
        const ushort_t* g = W + (size_t)(bn + row) * 1024 + kt * 64 + h * 32 + sg * 8;
        __builtin_amdgcn_global_load_lds(
            (const __attribute__((address_space(1))) void*)g,
            (__attribute__((address_space(3))) void*)(buf + 16384 + h * (BN * 32) + (size_t)c * 8),
            16, 0, 0);
    };

#define GPHASE(KK, MH, STAGE_STMT)                                           \
    {                                                                        \
        bf16x8 af[4];                                                        \
        _Pragma("unroll")                                                    \
        for (int j = 0; j < 4; ++j) {                                        \
            int row = wr * 128 + ((MH) * 4 + j) * 16 + fr;                   \
            af[j] = *(const bf16x8*)(As + (KK) * 8192 + row * 32 +           \
                                     ((hi ^ ((row >> 1) & 3))) * 8);         \
        }                                                                    \
        if ((MH) == 0) {                                                     \
            _Pragma("unroll")                                                \
            for (int nf = 0; nf < NF; ++nf) {                                \
                int row = wc * (BN / 4) + nf * 16 + fr;                      \
                if (BN == 192)                                               \
                    bw[nf] = *(const bf16x8*)(Bs + row * 64 +                \
                                 (((KK) * 4 + hi) ^ (row & 7)) * 8);         \
                else                                                         \
                    bw[nf] = *(const bf16x8*)(Bs + (KK) * (BN * 32) + row * 32 + \
                                 ((hi ^ ((row >> 1) & 3))) * 8);             \
            }                                                                \
        }                                                                    \
        STAGE_STMT;                                                          \
        __builtin_amdgcn_s_barrier();                                        \
        asm volatile("s_waitcnt lgkmcnt(0)" ::: "memory");                   \
        __builtin_amdgcn_sched_barrier(0);                                   \
        __builtin_amdgcn_s_setprio(1);                                       \
        _Pragma("unroll")                                                    \
        for (int j = 0; j < 4; ++j)                                          \
            _Pragma("unroll")                                                \
            for (int nf = 0; nf < NF; ++nf)                                  \
                acc[(MH) * 4 + j][nf] = __builtin_amdgcn_mfma_f32_16x16x32_bf16( \
                    af[j], bw[nf], acc[(MH) * 4 + j][nf], 0, 0, 0);          \
        __builtin_amdgcn_s_setprio(0);                                       \
        __builtin_amdgcn_s_barrier();                                        \
    }

    if constexpr (BN == 192) {
        SBfull(0, lds); SA(0, lds, 0); SA(0, lds, 1);
    } else {
        SA(0, lds, 0); SBh(0, lds, 0); SA(0, lds, 1); SBh(0, lds, 1);
    }

    for (int tt = 0; tt < NTK; ++tt) {
        ushort_t* base = lds + (tt & 1) * BUFU;
        ushort_t* nbuf = lds + ((tt + 1) & 1) * BUFU;
        const ushort_t* As = base;
        const ushort_t* Bs = base + 16384;
        const bool st = (tt + 1 < NTK);
        bf16x8 bw[NF];

        if constexpr (BN == 192) asm volatile("s_waitcnt vmcnt(2)" ::: "memory");
        else                     asm volatile("s_waitcnt vmcnt(3)" ::: "memory");
        __builtin_amdgcn_s_barrier();

        if constexpr (BN == 192) {
            GPHASE(0, 0, if (st) SBfull(tt + 1, nbuf));
            GPHASE(0, 1, if (st) SA(tt + 1, nbuf, 0));
        } else {
            GPHASE(0, 0, if (st) SA(tt + 1, nbuf, 0));
            GPHASE(0, 1, if (st) SBh(tt + 1, nbuf, 0));
        }

        if (st) {
            if constexpr (BN == 192) asm volatile("s_waitcnt vmcnt(5)" ::: "memory");
            else                     asm volatile("s_waitcnt vmcnt(3)" ::: "memory");
        } else {
            asm volatile("s_waitcnt vmcnt(0)" ::: "memory");
        }
        __builtin_amdgcn_s_barrier();

        if constexpr (BN == 192) {
            GPHASE(1, 0, if (st) SA(tt + 1, nbuf, 1));
            GPHASE(1, 1, );
        } else {
            GPHASE(1, 0, if (st) SA(tt + 1, nbuf, 1));
            GPHASE(1, 1, if (st) SBh(tt + 1, nbuf, 1));
        }
    }
#undef GPHASE

    const int fc = fr;
    const int r0 = hi * 4;
    #pragma unroll
    for (int m2 = 0; m2 < 8; ++m2)
        #pragma unroll
        for (int n2 = 0; n2 < NF; ++n2) {
            int col = bn + wc * (BN / 4) + n2 * 16 + fc;
            float bv;
            if (MODE == 6) bv = (col < 1024) ? bias[col] : 0.0f;
            else           bv = bias[col];
            #pragma unroll
            for (int r = 0; r < 4; ++r) {
                int row = bm + wr * 128 + m2 * 16 + r0 + r;
                size_t idx = (size_t)row * N + col;
                float v = acc[m2][n2][r] + bv;
                if (MODE == 4) ((float*)Cout)[idx] = v + bf2f(resid[idx]);
                else           ((ushort_t*)Cout)[idx] = f2bf(v);
            }
        }
}

// ---------------------------------------------------------------------------
// Cooperative fused scan: phase+chunk-sums | grid.sync | chunk prefix |
// grid.sync | scan+retrieved+LN (single block barrier).
// Grid 512 blocks x 256 thr (co-resident: tiny LDS, ~130 VGPR).
// Math identical to R16's three kernels.
// ---------------------------------------------------------------------------
__global__ __launch_bounds__(256)
void scan_all_k(const ushort_t* __restrict__ act3, const float* __restrict__ bp,
                const float* __restrict__ bck, const float* __restrict__ bcq,
                const float* __restrict__ ms_p,
                float* __restrict__ sumr, float* __restrict__ sumi,
                const float* __restrict__ g, const float* __restrict__ beta,
                ushort_t* __restrict__ normbf)
{
    const int blk = blockIdx.x;        // b*CHUNKS + c
    const int b = blk >> 7;
    const int c = blk & (CHUNKS - 1);
    const int t = threadIdx.x;
    const int d0 = t * 4;
    const float ms = ms_p[0];
    const float4 bk4 = *(const float4*)(bck + d0);
    const size_t row0 = (size_t)b * SEQ + (size_t)c * CLEN;
    const int wv = t >> 6, lane = t & 63;

    // ---------------- Phase A: chunk sums (ex-phase_scan1) ----------------
    {
        const float4 bc4 = bk4;
        float sr0 = 0.f, sr1 = 0.f, sr2 = 0.f, sr3 = 0.f;
        float si0 = 0.f, si1 = 0.f, si2 = 0.f, si3 = 0.f;
        #pragma unroll 2
        for (int s = 0; s < CLEN; ++s) {
            size_t row = row0 + s;
            ushort4 v4 = *(const ushort4*)(act3 + row * N3 + d0);
            ushort4 k4 = *(const ushort4*)(act3 + row * N3 + 1024 + d0);
            float4 bp4 = *(const float4*)(bp + ((size_t)(c * CLEN + s)) * DIM + d0);
            float vv, kp, sn, cs;
            vv = bf2f(v4.x); kp = bp4.x + (bf2f(k4.x) + bc4.x) * ms;
            __sincosf(kp, &sn, &cs); sr0 += vv * cs; si0 += vv * sn;
            vv = bf2f(v4.y); kp = bp4.y + (bf2f(k4.y) + bc4.y) * ms;
            __sincosf(kp, &sn, &cs); sr1 += vv * cs; si1 += vv * sn;
            vv = bf2f(v4.z); kp = bp4.z + (bf2f(k4.z) + bc4.z) * ms;
            __sincosf(kp, &sn, &cs); sr2 += vv * cs; si2 += vv * sn;
            vv = bf2f(v4.w); kp = bp4.w + (bf2f(k4.w) + bc4.w) * ms;
            __sincosf(kp, &sn, &cs); sr3 += vv * cs; si3 += vv * sn;
        }
        int sgid = (b * CHUNKS + c) * DIM + d0;
        *(float4*)(sumr + sgid) = make_float4(sr0, sr1, sr2, sr3);
        *(float4*)(sumi + sgid) = make_float4(si0, si1, si2, si3);
    }

    cooperative_groups::this_grid().sync();

    // ---------------- Phase B: chunk exclusive prefix (ex-scan_pass2) ------
    // 4096 (b,d) jobs over 2048 waves -> 2 jobs per wave.
    {
        int wgid = blk * 4 + wv;                 // 0..2047
        #pragma unroll
        for (int j = 0; j < 2; ++j) {
            int job = wgid + j * 2048;           // 0..4095
            int jb = job >> 10;
            int jd = job & (DIM - 1);
            int i0 = (jb * CHUNKS + 2 * lane) * DIM + jd;
            int i1 = i0 + DIM;
            float r0 = sumr[i0], r1 = sumr[i1];
            float s0 = sumi[i0], s1 = sumi[i1];
            float pr = r0 + r1, pi = s0 + s1;
            float er = pr, ei = pi;
            #pragma unroll
            for (int o = 1; o < 64; o <<= 1) {
                float tr = __shfl_up(er, o);
                float ti = __shfl_up(ei, o);
                if (lane >= o) { er += tr; ei += ti; }
            }
            er -= pr; ei -= pi;
            sumr[i0] = er;       sumi[i0] = ei;
            sumr[i1] = er + r0;  sumi[i1] = ei + s0;
        }
    }

    cooperative_groups::this_grid().sync();

    // ---------------- Phase C: scan + retrieved + LN (ex-scan3_ln) --------
    {
        const float4 bq4 = *(const float4*)(bcq + d0);
        const float inv_sqrt_dim = 0.03125f;
        int sgid = (b * CHUNKS + c) * DIM + d0;
        float4 rrv = *(const float4*)(sumr + sgid);
        float4 riv = *(const float4*)(sumi + sgid);
        float rr0 = rrv.x, rr1 = rrv.y, rr2 = rrv.z, rr3 = rrv.w;
        float ri0 = riv.x, ri1 = riv.y, ri2 = riv.z, ri3 = riv.w;

        __shared__ float red[CLEN][8];
        float retr[CLEN][4];

        ushort4 v4 = *(const ushort4*)(act3 + row0 * N3 + d0);
        ushort4 k4 = *(const ushort4*)(act3 + row0 * N3 + 1024 + d0);
        ushort4 q4 = *(const ushort4*)(act3 + row0 * N3 + 2048 + d0);
        float4  bp4 = *(const float4*)(bp + (size_t)(c * CLEN) * DIM + d0);

        #pragma unroll
        for (int s = 0; s < CLEN; ++s) {
            ushort4 vc = v4, kc4 = k4, qc = q4; float4 bpc = bp4;
            if (s + 1 < CLEN) {
                size_t row = row0 + s + 1;
                v4  = *(const ushort4*)(act3 + row * N3 + d0);
                k4  = *(const ushort4*)(act3 + row * N3 + 1024 + d0);
                q4  = *(const ushort4*)(act3 + row * N3 + 2048 + d0);
                bp4 = *(const float4*)(bp + (size_t)(c * CLEN + s + 1) * DIM + d0);
            }
            float vv, kp, qp, sk, ck, sq, cq;
            vv = bf2f(vc.x); kp = bpc.x + (bf2f(kc4.x) + bk4.x) * ms;
            __sincosf(kp, &sk, &ck); rr0 += vv * ck; ri0 += vv * sk;
            qp = bpc.x + (bf2f(qc.x) + bq4.x) * ms; __sincosf(qp, &sq, &cq);
            retr[s][0] = (rr0 * cq + ri0 * sq) * inv_sqrt_dim;
            vv = bf2f(vc.y); kp = bpc.y + (bf2f(kc4.y) + bk4.y) * ms;
            __sincosf(kp, &sk, &ck); rr1 += vv * ck; ri1 += vv * sk;
            qp = bpc.y + (bf2f(qc.y) + bq4.y) * ms; __sincosf(qp, &sq, &cq);
            retr[s][1] = (rr1 * cq + ri1 * sq) * inv_sqrt_dim;
            vv = bf2f(vc.z); kp = bpc.z + (bf2f(kc4.z) + bk4.z) * ms;
            __sincosf(kp, &sk, &ck); rr2 += vv * ck; ri2 += vv * sk;
            qp = bpc.z + (bf2f(qc.z) + bq4.z) * ms; __sincosf(qp, &sq, &cq);
            retr[s][2] = (rr2 * cq + ri2 * sq) * inv_sqrt_dim;
            vv = bf2f(vc.w); kp = bpc.w + (bf2f(kc4.w) + bk4.w) * ms;
            __sincosf(kp, &sk, &ck); rr3 += vv * ck; ri3 += vv * sk;
            qp = bpc.w + (bf2f(qc.w) + bq4.w) * ms; __sincosf(qp, &sq, &cq);
            retr[s][3] = (rr3 * cq + ri3 * sq) * inv_sqrt_dim;

            float ssum = retr[s][0] + retr[s][1] + retr[s][2] + retr[s][3];
            float ssq  = retr[s][0]*retr[s][0] + retr[s][1]*retr[s][1]
                       + retr[s][2]*retr[s][2] + retr[s][3]*retr[s][3];
            #pragma unroll
            for (int o = 32; o >= 1; o >>= 1) {
                ssum += __shfl_down(ssum, o);
                ssq  += __shfl_down(ssq, o);
            }
            if (lane == 0) { red[s][wv] = ssum; red[s][wv + 4] = ssq; }
        }

        __syncthreads();

        const float4 gv  = *(const float4*)(g + d0);
        const float4 btv = *(const float4*)(beta + d0);
        #pragma unroll
        for (int s = 0; s < CLEN; ++s) {
            float S  = ((red[s][0] + red[s][1]) + red[s][2]) + red[s][3];
            float SS = ((red[s][4] + red[s][5]) + red[s][6]) + red[s][7];
            float mu  = S * (1.0f / DIM);
            float var = SS * (1.0f / DIM) - mu * mu;
            float rstd = rsqrtf(var + LN_EPS);
            ushort4 o;
            o.x = f2bf((retr[s][0] - mu) * rstd * gv.x + btv.x);
            o.y = f2bf((retr[s][1] - mu) * rstd * gv.y + btv.y);
            o.z = f2bf((retr[s][2] - mu) * rstd * gv.z + btv.z);
            o.w = f2bf((retr[s][3] - mu) * rstd * gv.w + btv.w);
            *(ushort4*)(normbf + (row0 + s) * DIM + d0) = o;
        }
    }
}

// ---------------------------------------------------------------------------
extern "C" void kernel_launch(void* const* d_in, const int* in_sizes, int n_in,
                              void* d_out, int out_size, void* d_ws, size_t ws_size,
                              hipStream_t stream)
{
    const float* x   = (const float*)d_in[0];
    const float* bp  = (const float*)d_in[1];
    const float* Wk  = (const float*)d_in[2];
    const float* bk  = (const float*)d_in[3];
    const float* Wv  = (const float*)d_in[4];
    const float* bv  = (const float*)d_in[5];
    const float* Wq  = (const float*)d_in[6];
    const float* bq  = (const float*)d_in[7];
    const float* Wkm = (const float*)d_in[8];
    const float* bkm = (const float*)d_in[9];
    const float* Wqm = (const float*)d_in[10];
    const float* bqm = (const float*)d_in[11];
    const float* ms  = (const float*)d_in[12];
    const float* lng = (const float*)d_in[13];
    const float* lnb = (const float*)d_in[14];
    const float* Wo  = (const float*)d_in[15];
    const float* bo  = (const float*)d_in[16];
    float* out = (float*)d_out;

    // workspace layout
    ushort_t* act3   = (ushort_t*)d_ws;              // 50.3MB [value|kplin|qplin]
    ushort_t* xbf    = act3 + (size_t)ROWS * N3;     // 16.8MB
    ushort_t* normbf = xbf + NE;                     // 16.8MB
    ushort_t* W3     = normbf + NE;                  // 6.3MB (3072 x 1024)
    ushort_t* wo_b   = W3 + (size_t)N3 * DIM;        // 2.1MB
    ushort_t* wkm_b  = wo_b + WN;
    ushort_t* wqm_b  = wkm_b + WN;
    ushort_t* wkT_b  = wqm_b + WN;
    ushort_t* wqT_b  = wkT_b + WN;
    float* bck       = (float*)(wqT_b + WN);         // 4KB
    float* bcq       = bck + DIM;
    float* sumr      = bcq + DIM;                    // 2MB each
    float* sumi      = sumr + (size_t)BATCH * CHUNKS * DIM;

    // --- all prep (conv + transpose + matvec) in one dispatch ---
    prep_all_k<<<8704, 256, 0, stream>>>(x, Wv, Wo, Wkm, Wqm, Wk, Wq,
                                         bk, bkm, bq, bqm,
                                         xbf, W3, wo_b, wkm_b, wqm_b,
                                         wkT_b, wqT_b, bck, bcq);

    // --- both weight combines: W3 rows 1024..2047 and 2048..3071 ---
    dim3 gw(DIM / 128, DIM / 128, 2);
    gemm_combine2<<<gw, 256, 0, stream>>>(wkm_b, wkT_b, W3 + WN,
                                          wqm_b, wqT_b, W3 + 2 * WN);

    // --- fused activation GEMM: 256x192 tiles, grid (32,16)=512 = 2/CU ---
    dim3 g3(32, N3 / 192);
    gemm_pipe<6, 192><<<g3, 512, 0, stream>>>(xbf, W3, bv, nullptr, act3, N3);

    // --- fused scan (phase+sums | prefix | scan+LN), cooperative ---
    {
        void* args[] = { (void*)&act3, (void*)&bp, (void*)&bck, (void*)&bcq,
                         (void*)&ms, (void*)&sumr, (void*)&sumi,
                         (void*)&lng, (void*)&lnb, (void*)&normbf };
        hipLaunchCooperativeKernel((void*)scan_all_k, dim3(BATCH * CHUNKS),
                                   dim3(256), args, 0, stream);
    }

    // --- out = x + normed @ Wo^T + bo: 256x128 tiles, grid (32,8)=256 = 1/CU ---
    dim3 gg(32, DIM / 128);
    gemm_pipe<4, 128><<<gg, 512, 0, stream>>>(normbf, wo_b, bo, xbf, out, DIM);
}

// Round 18
// 163.253 us; speedup vs baseline: 1.7704x; 1.7704x over previous
//
#include <hip/hip_runtime.h>
#include <math.h>

#define DIM 1024
#define SEQ 2048
#define BATCH 4
#define ROWS (BATCH*SEQ)        // 8192
#define CHUNKS 128
#define CLEN (SEQ/CHUNKS)       // 16
#define N3 3072                 // fused act width: [value | kplin | qplin]
#define LN_EPS 1e-5f
#define NTK 16                  // K/BK = 1024/64 K-tiles

typedef unsigned short ushort_t;
typedef __attribute__((ext_vector_type(8))) short bf16x8;
typedef __attribute__((ext_vector_type(4))) float f32x4;

static const size_t NE = (size_t)ROWS * DIM;   // 8.4M
static const size_t WN = (size_t)DIM * DIM;    // 1M

// fp32 -> bf16 round-to-nearest-even
__device__ inline ushort_t f2bf(float f) {
    union { float f; unsigned u; } v; v.f = f;
    unsigned r = v.u + 0x7FFFu + ((v.u >> 16) & 1u);
    return (ushort_t)(r >> 16);
}
__device__ inline float bf2f(ushort_t u) { return __uint_as_float((unsigned)u << 16); }

// ---------------------------------------------------------------------------
// ALL prep work in one dispatch (block-range indexed, block-uniform):
//   blocks [0, 6144)        : fp32->bf16 conv  x | Wv | Wo | Wkm | Wqm
//   blocks [6144, 8192)     : transposed conv Wk, Wq  (32x32 tiles)
//   blocks [8192, 8704)     : combined-bias matvecs bck, bcq
// ---------------------------------------------------------------------------
__global__ __launch_bounds__(256)
void prep_all_k(const float* __restrict__ x,   const float* __restrict__ Wv,
                const float* __restrict__ Wo,  const float* __restrict__ Wkm,
                const float* __restrict__ Wqm, const float* __restrict__ Wk,
                const float* __restrict__ Wq,  const float* __restrict__ bk,
                const float* __restrict__ bkm, const float* __restrict__ bq,
                const float* __restrict__ bqm,
                ushort_t* __restrict__ xbf,   ushort_t* __restrict__ W3,
                ushort_t* __restrict__ wo_b,  ushort_t* __restrict__ wkm_b,
                ushort_t* __restrict__ wqm_b, ushort_t* __restrict__ wkT,
                ushort_t* __restrict__ wqT,
                float* __restrict__ bck, float* __restrict__ bcq)
{
    const int blk = blockIdx.x;
    const int t = threadIdx.x;
    __shared__ ushort_t tile[32][33];

    if (blk < 6144) {
        size_t e = ((size_t)blk * 256 + t) * 8;
        const float* src; ushort_t* dst; size_t off;
        if      (e < NE)          { src = x;   dst = xbf;   off = e; }
        else if (e < NE + WN)     { src = Wv;  dst = W3;    off = e - NE; }
        else if (e < NE + 2*WN)   { src = Wo;  dst = wo_b;  off = e - NE - WN; }
        else if (e < NE + 3*WN)   { src = Wkm; dst = wkm_b; off = e - NE - 2*WN; }
        else                      { src = Wqm; dst = wqm_b; off = e - NE - 3*WN; }
        float4 a = *(const float4*)(src + off);
        float4 b = *(const float4*)(src + off + 4);
        ushort4 lo, hi;
        lo.x = f2bf(a.x); lo.y = f2bf(a.y); lo.z = f2bf(a.z); lo.w = f2bf(a.w);
        hi.x = f2bf(b.x); hi.y = f2bf(b.y); hi.z = f2bf(b.z); hi.w = f2bf(b.w);
        *(ushort4*)(dst + off) = lo;
        *(ushort4*)(dst + off + 4) = hi;
    } else if (blk < 8192) {
        int tb = blk - 6144;                  // 0..2047
        const float* in = (tb >> 10) ? Wq : Wk;
        ushort_t* out   = (tb >> 10) ? wqT : wkT;
        int tid = tb & 1023;
        int bx = tid & 31, by = tid >> 5;
        int tx = t & 31, ty = t >> 5;         // 32x8
        #pragma unroll
        for (int j = 0; j < 4; ++j) {
            int r = by * 32 + ty + j * 8;
            tile[ty + j * 8][tx] = f2bf(in[(size_t)r * DIM + bx * 32 + tx]);
        }
        __syncthreads();
        #pragma unroll
        for (int j = 0; j < 4; ++j) {
            int r = bx * 32 + ty + j * 8;
            out[(size_t)r * DIM + by * 32 + tx] = tile[tx][ty + j * 8];
        }
    } else {
        int mb = blk - 8192;                  // 0..511
        int z = mb >> 8;
        const float* Wm  = z ? Wqm : Wkm;
        const float* bi  = z ? bq  : bk;
        const float* bo_ = z ? bqm : bkm;
        float* bc        = z ? bcq : bck;
        int e = (mb & 255) * 4 + (t >> 6);
        int l = t & 63;
        float s = 0.f;
        #pragma unroll
        for (int j = 0; j < DIM / 64; ++j)
            s += Wm[(size_t)e * DIM + l + j * 64] * bi[l + j * 64];
        #pragma unroll
        for (int o = 32; o >= 1; o >>= 1) s += __shfl_down(s, o);
        if (l == 0) bc[e] = s + bo_[e];
    }
}

// ---------------------------------------------------------------------------
// Dual weight-combine GEMM (m97 structure), z selects (Wkm@Wk | Wqm@Wq).
// ---------------------------------------------------------------------------
__global__ __launch_bounds__(256)
void gemm_combine2(const ushort_t* __restrict__ A0, const ushort_t* __restrict__ W0,
                   ushort_t* __restrict__ C0,
                   const ushort_t* __restrict__ A1, const ushort_t* __restrict__ W1,
                   ushort_t* __restrict__ C1)
{
    const ushort_t* A = blockIdx.z ? A1 : A0;
    const ushort_t* W = blockIdx.z ? W1 : W0;
    ushort_t*       C = blockIdx.z ? C1 : C0;
    __shared__ ushort_t As[128 * 32];
    __shared__ ushort_t Bs[128 * 32];
    const int bm = blockIdx.x * 128;
    const int bn = blockIdx.y * 128;
    const int t = threadIdx.x;
    const int lane = t & 63;
    const int w = t >> 6, wr = w >> 1, wc = w & 1;
    f32x4 acc[4][4] = {};
    const int fr = lane & 15;
    const int kc = (lane >> 4) * 8;
    for (int k0 = 0; k0 < DIM; k0 += 32) {
        #pragma unroll
        for (int i = 0; i < 2; ++i) {
            int c = t + i * 256;
            int row = c >> 2;
            int col = (c & 3) * 8;
            const ushort_t* ga = A + (size_t)(bm + row) * DIM + k0 + col;
            __builtin_amdgcn_global_load_lds(
                (const __attribute__((address_space(1))) void*)ga,
                (__attribute__((address_space(3))) void*)(As + (size_t)c * 8), 16, 0, 0);
            const ushort_t* gb = W + (size_t)(bn + row) * DIM + k0 + col;
            __builtin_amdgcn_global_load_lds(
                (const __attribute__((address_space(1))) void*)gb,
                (__attribute__((address_space(3))) void*)(Bs + (size_t)c * 8), 16, 0, 0);
        }
        __syncthreads();
        bf16x8 af[4], bw[4];
        #pragma unroll
        for (int m2 = 0; m2 < 4; ++m2)
            af[m2] = *(const bf16x8*)(As + (wr * 64 + m2 * 16 + fr) * 32 + kc);
        #pragma unroll
        for (int n2 = 0; n2 < 4; ++n2)
            bw[n2] = *(const bf16x8*)(Bs + (wc * 64 + n2 * 16 + fr) * 32 + kc);
        #pragma unroll
        for (int m2 = 0; m2 < 4; ++m2)
            #pragma unroll
            for (int n2 = 0; n2 < 4; ++n2)
                acc[m2][n2] = __builtin_amdgcn_mfma_f32_16x16x32_bf16(
                    af[m2], bw[n2], acc[m2][n2], 0, 0, 0);
        __syncthreads();
    }
    const int fc = lane & 15;
    const int r0 = (lane >> 4) * 4;
    #pragma unroll
    for (int m2 = 0; m2 < 4; ++m2)
        #pragma unroll
        for (int n2 = 0; n2 < 4; ++n2) {
            int col = bn + wc * 64 + n2 * 16 + fc;
            #pragma unroll
            for (int r = 0; r < 4; ++r) {
                int row = bm + wr * 64 + m2 * 16 + r0 + r;
                C[(size_t)row * DIM + col] = f2bf(acc[m2][n2][r]);
            }
        }
}

// ---------------------------------------------------------------------------
// 8-phase counted-vmcnt bf16 MFMA GEMM (NT), K=1024, BM=256, BN in {192,128}.
// (R10/R12 structure verbatim - verified 0 conflicts, minimal FETCH, 831 TF.)
// MODE 6: bf16 out, +bias col<1024.  MODE 4: f32 out, +bias, +bf16 resid.
// ---------------------------------------------------------------------------
template<int MODE, int BN>
__global__ __launch_bounds__(512)
void gemm_pipe(const ushort_t* __restrict__ A, const ushort_t* __restrict__ W,
               const float* __restrict__ bias, const ushort_t* __restrict__ resid,
               void* __restrict__ Cout, int N)
{
    constexpr int NF   = BN / 64;                 // n-frags per wave (3 or 2)
    constexpr int BUFU = 16384 + BN * 64;         // ushorts per buffer
    __shared__ __align__(16) ushort_t lds[2 * BUFU];

    const int bm = blockIdx.x * 256;
    const int bn = blockIdx.y * BN;
    const int t = threadIdx.x;          // 0..511
    const int lane = t & 63;
    const int w = t >> 6;               // 0..7
    const int wr = w >> 2;              // 0..1 (M)
    const int wc = w & 3;               // 0..3 (N)
    const int fr = lane & 15;
    const int hi = lane >> 4;           // 0..3

    f32x4 acc[8][NF] = {};

    auto SA = [&](int kt, ushort_t* buf, int h) {
        #pragma unroll
        for (int i = 0; i < 2; ++i) {
            int c = t + i * 512;                  // 0..1023
            int row = c >> 2, sl = c & 3, sg = sl ^ ((row >> 1) & 3);
            const ushort_t* g = A + (size_t)(bm + row) * 1024 + kt * 64 + h * 32 + sg * 8;
            __builtin_amdgcn_global_load_lds(
                (const __attribute__((address_space(1))) void*)g,
                (__attribute__((address_space(3))) void*)(buf + h * 8192 + (size_t)c * 8),
                16, 0, 0);
        }
    };
    auto SBfull = [&](int kt, ushort_t* buf) {
        #pragma unroll
        for (int i = 0; i < 3; ++i) {
            int c = t + i * 512;                  // 0..1535
            int row = c >> 3, sl = c & 7, sg = sl ^ (row & 7);
            const ushort_t* g = W + (size_t)(bn + row) * 1024 + kt * 64 + sg * 8;
            __builtin_amdgcn_global_load_lds(
                (const __attribute__((address_space(1))) void*)g,
                (__attribute__((address_space(3))) void*)(buf + 16384 + (size_t)c * 8),
                16, 0, 0);
        }
    };
    auto SBh = [&](int kt, ushort_t* buf, int h) {
        int c = t;                                // 0..511
        int row = c >> 2, sl = c & 3, sg = sl ^ ((row >> 1) & 3);
        const ushort_t* g = W + (size_t)(bn + row) * 1024 + kt * 64 + h * 32 + sg * 8;
        __builtin_amdgcn_global_load_lds(
            (const __attribute__((address_space(1))) void*)g,
            (__attribute__((address_space(3))) void*)(buf + 16384 + h * (BN * 32) + (size_t)c * 8),
            16, 0, 0);
    };

#define GPHASE(KK, MH, STAGE_STMT)                                           \
    {                                                                        \
        bf16x8 af[4];                                                        \
        _Pragma("unroll")                                                    \
        for (int j = 0; j < 4; ++j) {                                        \
            int row = wr * 128 + ((MH) * 4 + j) * 16 + fr;                   \
            af[j] = *(const bf16x8*)(As + (KK) * 8192 + row * 32 +           \
                                     ((hi ^ ((row >> 1) & 3))) * 8);         \
        }                                                                    \
        if ((MH) == 0) {                                                     \
            _Pragma("unroll")                                                \
            for (int nf = 0; nf < NF; ++nf) {                                \
                int row = wc * (BN / 4) + nf * 16 + fr;                      \
                if (BN == 192)                                               \
                    bw[nf] = *(const bf16x8*)(Bs + row * 64 +                \
                                 (((KK) * 4 + hi) ^ (row & 7)) * 8);         \
                else                                                         \
                    bw[nf] = *(const bf16x8*)(Bs + (KK) * (BN * 32) + row * 32 + \
                                 ((hi ^ ((row >> 1) & 3))) * 8);             \
            }                                                                \
        }                                                                    \
        STAGE_STMT;                                                          \
        __builtin_amdgcn_s_barrier();                                        \
        asm volatile("s_waitcnt lgkmcnt(0)" ::: "memory");                   \
        __builtin_amdgcn_sched_barrier(0);                                   \
        __builtin_amdgcn_s_setprio(1);                                       \
        _Pragma("unroll")                                                    \
        for (int j = 0; j < 4; ++j)                                          \
            _Pragma("unroll")                                                \
            for (int nf = 0; nf < NF; ++nf)                                  \
                acc[(MH) * 4 + j][nf] = __builtin_amdgcn_mfma_f32_16x16x32_bf16( \
                    af[j], bw[nf], acc[(MH) * 4 + j][nf], 0, 0, 0);          \
        __builtin_amdgcn_s_setprio(0);                                       \
        __builtin_amdgcn_s_barrier();                                        \
    }

    if constexpr (BN == 192) {
        SBfull(0, lds); SA(0, lds, 0); SA(0, lds, 1);
    } else {
        SA(0, lds, 0); SBh(0, lds, 0); SA(0, lds, 1); SBh(0, lds, 1);
    }

    for (int tt = 0; tt < NTK; ++tt) {
        ushort_t* base = lds + (tt & 1) * BUFU;
        ushort_t* nbuf = lds + ((tt + 1) & 1) * BUFU;
        const ushort_t* As = base;
        const ushort_t* Bs = base + 16384;
        const bool st = (tt + 1 < NTK);
        bf16x8 bw[NF];

        if constexpr (BN == 192) asm volatile("s_waitcnt vmcnt(2)" ::: "memory");
        else                     asm volatile("s_waitcnt vmcnt(3)" ::: "memory");
        __builtin_amdgcn_s_barrier();

        if constexpr (BN == 192) {
            GPHASE(0, 0, if (st) SBfull(tt + 1, nbuf));
            GPHASE(0, 1, if (st) SA(tt + 1, nbuf, 0));
        } else {
            GPHASE(0, 0, if (st) SA(tt + 1, nbuf, 0));
            GPHASE(0, 1, if (st) SBh(tt + 1, nbuf, 0));
        }

        if (st) {
            if constexpr (BN == 192) asm volatile("s_waitcnt vmcnt(5)" ::: "memory");
            else                     asm volatile("s_waitcnt vmcnt(3)" ::: "memory");
        } else {
            asm volatile("s_waitcnt vmcnt(0)" ::: "memory");
        }
        __builtin_amdgcn_s_barrier();

        if constexpr (BN == 192) {
            GPHASE(1, 0, if (st) SA(tt + 1, nbuf, 1));
            GPHASE(1, 1, );
        } else {
            GPHASE(1, 0, if (st) SA(tt + 1, nbuf, 1));
            GPHASE(1, 1, if (st) SBh(tt + 1, nbuf, 1));
        }
    }
#undef GPHASE

    const int fc = fr;
    const int r0 = hi * 4;
    #pragma unroll
    for (int m2 = 0; m2 < 8; ++m2)
        #pragma unroll
        for (int n2 = 0; n2 < NF; ++n2) {
            int col = bn + wc * (BN / 4) + n2 * 16 + fc;
            float bv;
            if (MODE == 6) bv = (col < 1024) ? bias[col] : 0.0f;
            else           bv = bias[col];
            #pragma unroll
            for (int r = 0; r < 4; ++r) {
                int row = bm + wr * 128 + m2 * 16 + r0 + r;
                size_t idx = (size_t)row * N + col;
                float v = acc[m2][n2][r] + bv;
                if (MODE == 4) ((float*)Cout)[idx] = v + bf2f(resid[idx]);
                else           ((ushort_t*)Cout)[idx] = f2bf(v);
            }
        }
}

// ---------------------------------------------------------------------------
// Phase + chunk sums (no ab materialization), HW sincos.
// Block = (b, chunk); 256 thr x 4 d.
// ---------------------------------------------------------------------------
__global__ __launch_bounds__(256)
void phase_scan1_k(const ushort_t* __restrict__ act3, const float* __restrict__ bp,
                   const float* __restrict__ bck, const float* __restrict__ ms_p,
                   float* __restrict__ sumr, float* __restrict__ sumi)
{
    const int blk = blockIdx.x;        // b*CHUNKS + c
    const int b = blk >> 7;
    const int c = blk & (CHUNKS - 1);
    const int d0 = threadIdx.x * 4;
    const float ms = ms_p[0];
    const float4 bc4 = *(const float4*)(bck + d0);
    float sr0 = 0.f, sr1 = 0.f, sr2 = 0.f, sr3 = 0.f;
    float si0 = 0.f, si1 = 0.f, si2 = 0.f, si3 = 0.f;
    const size_t row0 = (size_t)b * SEQ + (size_t)c * CLEN;

    #pragma unroll 2
    for (int s = 0; s < CLEN; ++s) {
        size_t row = row0 + s;
        ushort4 v4 = *(const ushort4*)(act3 + row * N3 + d0);
        ushort4 k4 = *(const ushort4*)(act3 + row * N3 + 1024 + d0);
        float4 bp4 = *(const float4*)(bp + ((size_t)(c * CLEN + s)) * DIM + d0);
        float vv, kp, sn, cs;
        vv = bf2f(v4.x); kp = bp4.x + (bf2f(k4.x) + bc4.x) * ms;
        __sincosf(kp, &sn, &cs); sr0 += vv * cs; si0 += vv * sn;
        vv = bf2f(v4.y); kp = bp4.y + (bf2f(k4.y) + bc4.y) * ms;
        __sincosf(kp, &sn, &cs); sr1 += vv * cs; si1 += vv * sn;
        vv = bf2f(v4.z); kp = bp4.z + (bf2f(k4.z) + bc4.z) * ms;
        __sincosf(kp, &sn, &cs); sr2 += vv * cs; si2 += vv * sn;
        vv = bf2f(v4.w); kp = bp4.w + (bf2f(k4.w) + bc4.w) * ms;
        __sincosf(kp, &sn, &cs); sr3 += vv * cs; si3 += vv * sn;
    }
    int sgid = (b * CHUNKS + c) * DIM + d0;
    *(float4*)(sumr + sgid) = make_float4(sr0, sr1, sr2, sr3);
    *(float4*)(sumi + sgid) = make_float4(si0, si1, si2, si3);
}

// ---------------------------------------------------------------------------
// Scan pass 2: exclusive prefix over CHUNKS(=128) chunk-sums, 1 wave/(b,d),
// 2 chunks per lane.
// ---------------------------------------------------------------------------
__global__ __launch_bounds__(256)
void scan_pass2(float* __restrict__ sumr, float* __restrict__ sumi)
{
    int wid  = (blockIdx.x * 256 + threadIdx.x) >> 6;   // 0..4095 = (b,d)
    int lane = threadIdx.x & 63;
    int b = wid >> 10;
    int d = wid & (DIM - 1);
    int i0 = (b * CHUNKS + 2 * lane) * DIM + d;
    int i1 = i0 + DIM;
    float r0 = sumr[i0], r1 = sumr[i1];
    float s0 = sumi[i0], s1 = sumi[i1];
    float pr = r0 + r1, pi = s0 + s1;
    float er = pr, ei = pi;
    #pragma unroll
    for (int o = 1; o < 64; o <<= 1) {
        float tr = __shfl_up(er, o);
        float ti = __shfl_up(ei, o);
        if (lane >= o) { er += tr; ei += ti; }
    }
    er -= pr; ei -= pi;               // exclusive prefix over pairs
    sumr[i0] = er;       sumi[i0] = ei;
    sumr[i1] = er + r0;  sumi[i1] = ei + s0;
}

// ---------------------------------------------------------------------------
// Scan pass 3 + LayerNorm, single-barrier version (R16 verified).
// ---------------------------------------------------------------------------
__global__ __launch_bounds__(256)
void scan3_ln_k(const ushort_t* __restrict__ act3, const float* __restrict__ bp,
                const float* __restrict__ bck, const float* __restrict__ bcq,
                const float* __restrict__ ms_p,
                const float* __restrict__ sumr, const float* __restrict__ sumi,
                const float* __restrict__ g, const float* __restrict__ beta,
                ushort_t* __restrict__ normbf)
{
    const int blk = blockIdx.x;
    const int b = blk >> 7;
    const int c = blk & (CHUNKS - 1);
    const int t = threadIdx.x;
    const int d0 = t * 4;
    const float ms = ms_p[0];
    const float4 bk4 = *(const float4*)(bck + d0);
    const float4 bq4 = *(const float4*)(bcq + d0);
    const float inv_sqrt_dim = 0.03125f;

    int sgid = (b * CHUNKS + c) * DIM + d0;
    float4 rrv = *(const float4*)(sumr + sgid);
    float4 riv = *(const float4*)(sumi + sgid);
    float rr0 = rrv.x, rr1 = rrv.y, rr2 = rrv.z, rr3 = rrv.w;
    float ri0 = riv.x, ri1 = riv.y, ri2 = riv.z, ri3 = riv.w;

    const size_t row0 = (size_t)b * SEQ + (size_t)c * CLEN;
    __shared__ float red[CLEN][8];
    const int wv = t >> 6, lane = t & 63;

    float retr[CLEN][4];

    ushort4 v4 = *(const ushort4*)(act3 + row0 * N3 + d0);
    ushort4 k4 = *(const ushort4*)(act3 + row0 * N3 + 1024 + d0);
    ushort4 q4 = *(const ushort4*)(act3 + row0 * N3 + 2048 + d0);
    float4  bp4 = *(const float4*)(bp + (size_t)(c * CLEN) * DIM + d0);

    #pragma unroll
    for (int s = 0; s < CLEN; ++s) {
        ushort4 vc = v4, kc4 = k4, qc = q4; float4 bpc = bp4;
        if (s + 1 < CLEN) {
            size_t row = row0 + s + 1;
            v4  = *(const ushort4*)(act3 + row * N3 + d0);
            k4  = *(const ushort4*)(act3 + row * N3 + 1024 + d0);
            q4  = *(const ushort4*)(act3 + row * N3 + 2048 + d0);
            bp4 = *(const float4*)(bp + (size_t)(c * CLEN + s + 1) * DIM + d0);
        }
        float vv, kp, qp, sk, ck, sq, cq;
        vv = bf2f(vc.x); kp = bpc.x + (bf2f(kc4.x) + bk4.x) * ms;
        __sincosf(kp, &sk, &ck); rr0 += vv * ck; ri0 += vv * sk;
        qp = bpc.x + (bf2f(qc.x) + bq4.x) * ms; __sincosf(qp, &sq, &cq);
        retr[s][0] = (rr0 * cq + ri0 * sq) * inv_sqrt_dim;
        vv = bf2f(vc.y); kp = bpc.y + (bf2f(kc4.y) + bk4.y) * ms;
        __sincosf(kp, &sk, &ck); rr1 += vv * ck; ri1 += vv * sk;
        qp = bpc.y + (bf2f(qc.y) + bq4.y) * ms; __sincosf(qp, &sq, &cq);
        retr[s][1] = (rr1 * cq + ri1 * sq) * inv_sqrt_dim;
        vv = bf2f(vc.z); kp = bpc.z + (bf2f(kc4.z) + bk4.z) * ms;
        __sincosf(kp, &sk, &ck); rr2 += vv * ck; ri2 += vv * sk;
        qp = bpc.z + (bf2f(qc.z) + bq4.z) * ms; __sincosf(qp, &sq, &cq);
        retr[s][2] = (rr2 * cq + ri2 * sq) * inv_sqrt_dim;
        vv = bf2f(vc.w); kp = bpc.w + (bf2f(kc4.w) + bk4.w) * ms;
        __sincosf(kp, &sk, &ck); rr3 += vv * ck; ri3 += vv * sk;
        qp = bpc.w + (bf2f(qc.w) + bq4.w) * ms; __sincosf(qp, &sq, &cq);
        retr[s][3] = (rr3 * cq + ri3 * sq) * inv_sqrt_dim;

        float ssum = retr[s][0] + retr[s][1] + retr[s][2] + retr[s][3];
        float ssq  = retr[s][0]*retr[s][0] + retr[s][1]*retr[s][1]
                   + retr[s][2]*retr[s][2] + retr[s][3]*retr[s][3];
        #pragma unroll
        for (int o = 32; o >= 1; o >>= 1) {
            ssum += __shfl_down(ssum, o);
            ssq  += __shfl_down(ssq, o);
        }
        if (lane == 0) { red[s][wv] = ssum; red[s][wv + 4] = ssq; }
    }

    __syncthreads();   // the ONLY barrier

    const float4 gv  = *(const float4*)(g + d0);
    const float4 btv = *(const float4*)(beta + d0);
    #pragma unroll
    for (int s = 0; s < CLEN; ++s) {
        float S  = ((red[s][0] + red[s][1]) + red[s][2]) + red[s][3];
        float SS = ((red[s][4] + red[s][5]) + red[s][6]) + red[s][7];
        float mu  = S * (1.0f / DIM);
        float var = SS * (1.0f / DIM) - mu * mu;
        float rstd = rsqrtf(var + LN_EPS);
        ushort4 o;
        o.x = f2bf((retr[s][0] - mu) * rstd * gv.x + btv.x);
        o.y = f2bf((retr[s][1] - mu) * rstd * gv.y + btv.y);
        o.z = f2bf((retr[s][2] - mu) * rstd * gv.z + btv.z);
        o.w = f2bf((retr[s][3] - mu) * rstd * gv.w + btv.w);
        *(ushort4*)(normbf + (row0 + s) * DIM + d0) = o;
    }
}

// ---------------------------------------------------------------------------
extern "C" void kernel_launch(void* const* d_in, const int* in_sizes, int n_in,
                              void* d_out, int out_size, void* d_ws, size_t ws_size,
                              hipStream_t stream)
{
    const float* x   = (const float*)d_in[0];
    const float* bp  = (const float*)d_in[1];
    const float* Wk  = (const float*)d_in[2];
    const float* bk  = (const float*)d_in[3];
    const float* Wv  = (const float*)d_in[4];
    const float* bv  = (const float*)d_in[5];
    const float* Wq  = (const float*)d_in[6];
    const float* bq  = (const float*)d_in[7];
    const float* Wkm = (const float*)d_in[8];
    const float* bkm = (const float*)d_in[9];
    const float* Wqm = (const float*)d_in[10];
    const float* bqm = (const float*)d_in[11];
    const float* ms  = (const float*)d_in[12];
    const float* lng = (const float*)d_in[13];
    const float* lnb = (const float*)d_in[14];
    const float* Wo  = (const float*)d_in[15];
    const float* bo  = (const float*)d_in[16];
    float* out = (float*)d_out;

    // workspace layout
    ushort_t* act3   = (ushort_t*)d_ws;              // 50.3MB [value|kplin|qplin]
    ushort_t* xbf    = act3 + (size_t)ROWS * N3;     // 16.8MB
    ushort_t* normbf = xbf + NE;                     // 16.8MB
    ushort_t* W3     = normbf + NE;                  // 6.3MB (3072 x 1024)
    ushort_t* wo_b   = W3 + (size_t)N3 * DIM;        // 2.1MB
    ushort_t* wkm_b  = wo_b + WN;
    ushort_t* wqm_b  = wkm_b + WN;
    ushort_t* wkT_b  = wqm_b + WN;
    ushort_t* wqT_b  = wkT_b + WN;
    float* bck       = (float*)(wqT_b + WN);         // 4KB
    float* bcq       = bck + DIM;
    float* sumr      = bcq + DIM;                    // 2MB each
    float* sumi      = sumr + (size_t)BATCH * CHUNKS * DIM;

    // --- all prep (conv + transpose + matvec) in one dispatch ---
    prep_all_k<<<8704, 256, 0, stream>>>(x, Wv, Wo, Wkm, Wqm, Wk, Wq,
                                         bk, bkm, bq, bqm,
                                         xbf, W3, wo_b, wkm_b, wqm_b,
                                         wkT_b, wqT_b, bck, bcq);

    // --- both weight combines: W3 rows 1024..2047 and 2048..3071 ---
    dim3 gw(DIM / 128, DIM / 128, 2);
    gemm_combine2<<<gw, 256, 0, stream>>>(wkm_b, wkT_b, W3 + WN,
                                          wqm_b, wqT_b, W3 + 2 * WN);

    // --- fused activation GEMM: 256x192 tiles, grid (32,16)=512 = 2/CU ---
    dim3 g3(32, N3 / 192);
    gemm_pipe<6, 192><<<g3, 512, 0, stream>>>(xbf, W3, bv, nullptr, act3, N3);

    // --- phase + chunk sums ---
    phase_scan1_k<<<BATCH * CHUNKS, 256, 0, stream>>>(act3, bp, bck, ms,
                                                      sumr, sumi);
    // --- exclusive chunk prefix ---
    scan_pass2<<<(BATCH * DIM) / 4, 256, 0, stream>>>(sumr, sumi);
    // --- scan + retrieved + layernorm (single barrier) ---
    scan3_ln_k<<<BATCH * CHUNKS, 256, 0, stream>>>(act3, bp, bck, bcq, ms,
                                                   sumr, sumi, lng, lnb, normbf);

    // --- out = x + normed @ Wo^T + bo: 256x128 tiles, grid (32,8)=256 = 1/CU ---
    dim3 gg(32, DIM / 128);
    gemm_pipe<4, 128><<<gg, 512, 0, stream>>>(normbf, wo_b, bo, xbf, out, DIM);
}